// Round 8
// baseline (129.722 us; speedup 1.0000x reference)
//
#include <hip/hip_runtime.h>

#define CH 30
#define CELLS 49
#define ROWF 1470          // floats per batch row
#define WPB 2              // waves per block
#define NBLK 768           // persistent grid: 256 CU x 3 blocks (LDS-capped)
#define FULLI 22           // full 64-dword global_load_lds instrs per tensor-row
#define TAILL 62           // active lanes in tail instr (1470 - 22*64)
#define BUFF 1472          // padded row floats per tensor per buffer

__device__ __forceinline__ float waveReduce(float v) {
    #pragma unroll
    for (int o = 32; o > 0; o >>= 1) v += __shfl_xor(v, o, 64);
    return v;
}

// R8: persistent-wave double-buffered pipeline. Cross-round diagnosis: R1/R3/
// R7 (three different structures) all plateau at ~36us because one-shot waves
// have a low HBM duty cycle -- loads are only in flight during a short issue
// window, then the wave computes with the memory system idle. Fix: 1536
// persistent waves, each looping ~6 rows; row k+1 is staged into the alternate
// LDS buffer via fire-and-forget global_load_lds (no VGPR dest -> the R2/R4
// allocator-serialization failure mode cannot occur) WHILE row k is consumed
// from LDS. Counted s_waitcnt vmcnt(46) keeps k+1's 46 loads in flight across
// the whole consume (never drain to 0 mid-loop). LDS 50.7 KB/block -> exactly
// 3 blocks/CU resident; 6 waves/CU each with ~12 KB outstanding sustains the
// ~22 KB/CU in-flight bytes needed for near-peak read BW.
__global__ __launch_bounds__(128) void yolo_main(const float* __restrict__ pred,
                                                 const float* __restrict__ targ,
                                                 float* __restrict__ ws, int B,
                                                 int NW) {
    const int w = threadIdx.x >> 6;
    const int lane = threadIdx.x & 63;
    const int wid = blockIdx.x * WPB + w;

    __shared__ float stage[WPB][2][2][BUFF];   // [wave][buf][P=0/T=1][floats]
    __shared__ float4 boxS[WPB][2 * CELLS];    // pred boxes xyxy (broadcast)
    __shared__ int clist[WPB][CELLS];
    __shared__ float sred[WPB][3];

    float cls = 0.f, objc = 0.f, coord = 0.f;

    // ---- fire-and-forget staging of one row into LDS buffer `buf` ----
    auto issueRow = [&](int row, int buf) {
        const float* P = pred + (size_t)row * ROWF;
        const float* T = targ + (size_t)row * ROWF;
        float* lp = &stage[w][buf][0][0];
        float* lt = &stage[w][buf][1][0];
        #pragma unroll
        for (int k = 0; k < FULLI; ++k) {
            __builtin_amdgcn_global_load_lds(
                (const __attribute__((address_space(1))) float*)(P + k * 64 + lane),
                (__attribute__((address_space(3))) float*)(lp + k * 64), 4, 0, 0);
            __builtin_amdgcn_global_load_lds(
                (const __attribute__((address_space(1))) float*)(T + k * 64 + lane),
                (__attribute__((address_space(3))) float*)(lt + k * 64), 4, 0, 0);
        }
        if (lane < TAILL) {
            __builtin_amdgcn_global_load_lds(
                (const __attribute__((address_space(1))) float*)(P + FULLI * 64 + lane),
                (__attribute__((address_space(3))) float*)(lp + FULLI * 64), 4, 0, 0);
            __builtin_amdgcn_global_load_lds(
                (const __attribute__((address_space(1))) float*)(T + FULLI * 64 + lane),
                (__attribute__((address_space(3))) float*)(lt + FULLI * 64), 4, 0, 0);
        }
    };

    if (wid < B) issueRow(wid, 0);             // pipeline prologue

    int it = 0;
    for (int row = wid; row < B; row += NW, ++it) {
        const int cur = it & 1;
        const int nxt = row + NW;

        // ensure prior consume's ds_reads drained before DMA overwrites buf^1
        asm volatile("s_waitcnt lgkmcnt(0)" ::: "memory");
        if (nxt < B) {
            issueRow(nxt, cur ^ 1);
            asm volatile("s_waitcnt vmcnt(46)" ::: "memory"); // row k landed; k+1 in flight
        } else {
            asm volatile("s_waitcnt vmcnt(0)" ::: "memory");
        }

        // ---- consume row from LDS buffer `cur` ----
        const float* lp = &stage[w][cur][0][0];
        const float* lt = &stage[w][cur][1][0];

        // obj mask from staged t-conf
        const int cc = lane < CELLS ? lane : CELLS - 1;
        const bool isObj = (lane < CELLS) && (lt[cc * CH + 4] > 0.f);
        const unsigned long long m = __ballot(isObj);
        if (isObj) clist[w][__popcll(m & ((1ull << lane) - 1ull))] = lane;

        // one-pass stream: cls (obj cells) + noobj conf (0.5 folded)
        #pragma unroll
        for (int k = 0; k < 12; ++k) {
            const int q = lane + k * 64;
            if (q < 735) {
                const int cell = (q * 17477) >> 18;    // q/15, valid to 767
                const int ch0 = 2 * (q - cell * 15);
                const float wobj = (float)((m >> cell) & 1ull);
                const float2 pq = *(const float2*)(lp + 2 * q);
                const float2 tq = *(const float2*)(lt + 2 * q);
                const float dx = pq.x - tq.x, dy = pq.y - tq.y;
                cls += (ch0 >= 10) ? wobj * (dx * dx + dy * dy) : 0.f;
                const float nn = (ch0 == 4 ? dx * dx : 0.f)
                               + (ch0 == 8 ? dy * dy : 0.f);
                objc += 0.5f * (1.f - wobj) * nn;
            }
        }

        // box/IoU tail, LDS-sourced
        const int nBox = 2 * __popcll(m);
        if (nBox) {                              // wave-uniform
            for (int e = lane; e < nBox; e += 64) {
                const int c = clist[w][e >> 1];
                const float* pb = lp + c * CH + (e & 1) * 5;
                const float cx = pb[0], cy = pb[1], bw = pb[2], bh = pb[3];
                boxS[w][e] = make_float4(cx - 0.5f * bw, cy - 0.5f * bh,
                                         cx + 0.5f * bw, cy + 0.5f * bh);
            }
            for (int e = lane; e < nBox; e += 64) {
                const int c = clist[w][e >> 1];
                const float* tb = lt + c * CH + (e & 1) * 5;
                const float tcx = tb[0], tcy = tb[1], tw = tb[2], th = tb[3];
                const float tx1 = tcx - 0.5f * tw, ty1 = tcy - 0.5f * th;
                const float tx2 = tcx + 0.5f * tw, ty2 = tcy + 0.5f * th;
                const float ta = (tx2 - tx1) * (ty2 - ty1);
                float maxiou = 0.f;
                for (int i = 0; i < nBox; ++i) {
                    const float4 pb4 = boxS[w][i];   // uniform addr = broadcast
                    const float lx = fmaxf(pb4.x, tx1), ly = fmaxf(pb4.y, ty1);
                    const float rx = fminf(pb4.z, tx2), ry = fminf(pb4.w, ty2);
                    const float iw = fmaxf(rx - lx, 0.f), ih = fmaxf(ry - ly, 0.f);
                    const float inter = iw * ih;
                    const float pa = (pb4.z - pb4.x) * (pb4.w - pb4.y);
                    const float un = pa + ta - inter;
                    const float iou = inter / (un > 0.f ? un : 1.f);
                    maxiou = fmaxf(maxiou, iou);
                }
                if (maxiou != 0.f) {                 // cmask
                    const float* pb = lp + c * CH + (e & 1) * 5;
                    const float dcx = pb[0] - tcx, dcy = pb[1] - tcy;
                    coord += dcx * dcx + dcy * dcy;
                    const float dw = sqrtf(pb[2]) - sqrtf(tw);
                    const float dh = sqrtf(pb[3]) - sqrtf(th);
                    coord += dw * dw + dh * dh;
                    const float dc = pb[4] - tb[4];
                    objc += dc * dc;
                }
            }
        }
    }

    // ---- wave reduce, then block reduce (one barrier), one triple per block ----
    cls = waveReduce(cls); objc = waveReduce(objc); coord = waveReduce(coord);
    if (lane == 0) { sred[w][0] = cls; sred[w][1] = objc; sred[w][2] = coord; }
    __syncthreads();
    if (threadIdx.x == 0) {
        float C = 0.f, O = 0.f, X = 0.f;
        #pragma unroll
        for (int k = 0; k < WPB; ++k) { C += sred[k][0]; O += sred[k][1]; X += sred[k][2]; }
        ws[blockIdx.x] = C;
        ws[NBLK + blockIdx.x] = O;
        ws[2 * NBLK + blockIdx.x] = X;
    }
}

__global__ __launch_bounds__(1024) void yolo_reduce(const float* __restrict__ ws,
                                                    float* __restrict__ out,
                                                    int NB, float invB) {
    const int tid = threadIdx.x;
    const int w = tid >> 6, lane = tid & 63;
    float c = 0.f, o = 0.f, x = 0.f;
    for (int i = tid; i < NB; i += 1024) {
        c += ws[i];
        o += ws[NB + i];
        x += ws[2 * NB + i];
    }
    c = waveReduce(c); o = waveReduce(o); x = waveReduce(x);
    __shared__ float sred[16][3];
    if (lane == 0) { sred[w][0] = c; sred[w][1] = o; sred[w][2] = x; }
    __syncthreads();
    if (tid == 0) {
        float C = 0.f, O = 0.f, X = 0.f;
        #pragma unroll
        for (int k = 0; k < 16; ++k) { C += sred[k][0]; O += sred[k][1]; X += sred[k][2]; }
        const float bcls = C * invB;
        const float bobj = O * invB;          // noobj*0.5 folded upstream
        const float bcoord = X * 5.0f * invB; // COORD_LAMBDA
        out[0] = bcls + bobj + bcoord;
        out[1] = bcls;
        out[2] = bobj;
        out[3] = bcoord;
    }
}

extern "C" void kernel_launch(void* const* d_in, const int* in_sizes, int n_in,
                              void* d_out, int out_size, void* d_ws, size_t ws_size,
                              hipStream_t stream) {
    const float* pred = (const float*)d_in[0];
    const float* targ = (const float*)d_in[1];
    float* ws = (float*)d_ws;
    float* out = (float*)d_out;
    const int B = in_sizes[0] / ROWF;
    const int NW = NBLK * WPB;

    yolo_main<<<NBLK, 128, 0, stream>>>(pred, targ, ws, B, NW);
    yolo_reduce<<<1, 1024, 0, stream>>>(ws, out, NBLK, 1.0f / (float)B);
}